// Round 7
// baseline (180.861 us; speedup 1.0000x reference)
//
#include <hip/hip_runtime.h>

#define BB 256
#define TT 256
#define HH 64

typedef _Float16 half8 __attribute__((ext_vector_type(8)));
typedef _Float16 half4v __attribute__((ext_vector_type(4)));
typedef __fp16 fp16x2 __attribute__((ext_vector_type(2)));
typedef float floatx4 __attribute__((ext_vector_type(4)));

// ---------------------------------------------------------------------------
// prep: blocks 0..63   -> rpeh[i] = (f16) rpe[i]  (rows 0..255)
//       blocks 64..255 -> WT[(w*64+n)][k] = (f16) W_w[k][n]
// ---------------------------------------------------------------------------
__global__ __launch_bounds__(256) void prep(
    const float* __restrict__ rpe,
    const float* __restrict__ Wk, const float* __restrict__ Wq, const float* __restrict__ Wv,
    _Float16* __restrict__ rpeh, _Float16* __restrict__ WT)
{
    const int bid = blockIdx.x, tid = threadIdx.x;
    if (bid < 64) {
        const int i = bid * 256 + tid;
        rpeh[i] = (_Float16)rpe[i];
    } else {
        const int wsel = (bid - 64) >> 6;          // 0=k, 1=q, 2=v
        const int n    = (bid - 64) & 63;
        const float* W = wsel == 0 ? Wk : (wsel == 1 ? Wq : Wv);
        WT[(size_t)(wsel * 64 + n) * 256 + tid] = (_Float16)W[tid * HH + n];
    }
}

__device__ __forceinline__ half8 cvt8(const float4& a, const float4& b) {
    union H8 { half8 v; fp16x2 p[4]; } u;
    u.p[0] = __builtin_amdgcn_cvt_pkrtz(a.x, a.y);
    u.p[1] = __builtin_amdgcn_cvt_pkrtz(a.z, a.w);
    u.p[2] = __builtin_amdgcn_cvt_pkrtz(b.x, b.y);
    u.p[3] = __builtin_amdgcn_cvt_pkrtz(b.z, b.w);
    return u.v;
}

// ---------------------------------------------------------------------------
// fused r22: STRUCTURAL change after 4 neutral micro-rounds (r17-r21 all
// 43.4-46.5us; single 16-wave barrier domain = ~80% stall).  Grid 512 =
// 256 batches x 2 half-blocks (8 waves each, 51KB LDS -> 2 blocks/CU =
// two INDEPENDENT barrier domains; one drains, the other issues).
//   half0 (bid<256):  q-tiles 0..7,  K/V rows 0..127, s-chunks 0..1
//   half1 (bid>=256): q-tiles 8..15, K/V rows 0..255, s-chunks 0..3
// Shiftless softmax is linearly chunkable (no max): per 64-col s-chunk,
// sum+= and O+= with no rescale.  K/V projected into the OWNING wave's
// registers (fp16 packs), written per-chunk to double-buffered XOR-swizzled
// K_c/VT_c[64][64].  Each wave projects its OWN tile's Q -> q-transpose,
// pos skew-scatter, exp, PV all in a wave-PRIVATE slot [16][68] (68h = 34dw
// stride -> conflict-free strided reads; fixes r21's Vw=72 collision).
// Barriers: 2 staging + 1/chunk only; no cross-wave softmax sync at all.
// ---------------------------------------------------------------------------
template<int H>
__device__ __forceinline__ void run_half(
    const float* __restrict__ x, const _Float16* __restrict__ WT,
    const _Float16* __restrict__ rpeh, float* __restrict__ out,
    _Float16* lds, const int b, const int tid)
{
    constexpr int RPW = 16 << H;        // K/V rows projected per wave
    constexpr int NRT = 1 << H;         // K/V row-tiles per wave
    constexpr int NCH = 2 + 2 * H;      // s-chunks of 64
    constexpr int WPC = 4 >> H;         // writer waves per chunk

    _Float16* Kbuf = lds;               // 2 x [64][64] xor-swz (4096 h each)
    _Float16* Vbuf = lds + 8192;        // 2 x [64][64] xor-swz (VT)
    _Float16* pool = lds + 16384;       // 8 waves x [16][68] private slots

    const int w    = tid >> 6;
    const int lane = tid & 63;
    const int quad = lane >> 4;
    const int l    = lane & 15;
    const int t    = 8 * H + w;         // this wave's attention q-tile

    const float4* xg = reinterpret_cast<const float4*>(x);
    const int kvrow = b * 256 + RPW * w;      // wave's K/V x-rows
    const int qrow  = b * 256 + 16 * t;       // wave's Q x-rows (own tile)

    floatx4 akv[NRT][8];                // nt 0..3 = K cols, 4..7 = V cols
    floatx4 aq[4];
#pragma unroll
    for (int rt = 0; rt < NRT; ++rt)
#pragma unroll
        for (int nt = 0; nt < 8; ++nt) akv[rt][nt] = (floatx4){0.f,0.f,0.f,0.f};
#pragma unroll
    for (int nt = 0; nt < 4; ++nt) aq[nt] = (floatx4){0.f,0.f,0.f,0.f};

    // ---- phase 1: project K,V (own rows) + Q (own tile), 2 k-chunks ------
#pragma unroll
    for (int kc = 0; kc < 2; ++kc) {
        // stage W chunk kc: [192][136] halves (3072 granules / 512 thr = 6)
#pragma unroll
        for (int i = 0; i < 6; ++i) {
            const int gi = tid + i * 512, row = gi >> 4, g = gi & 15;
            *(half8*)&lds[row * 136 + g * 8] =
                *(const half8*)(WT + (size_t)row * 256 + kc * 128 + g * 8);
        }
        __syncthreads();

#pragma unroll
        for (int rt = 0; rt < NRT; ++rt) {
            const size_t xb = (size_t)(kvrow + rt * 16 + l) * 64 + kc * 32 + quad * 2;
            float4 a0 = xg[xb], a1 = xg[xb + 1];
#pragma unroll
            for (int kk = 0; kk < 4; ++kk) {
                float4 n0, n1;
                if (kk < 3) { n0 = xg[xb + (kk + 1) * 8]; n1 = xg[xb + (kk + 1) * 8 + 1]; }
                const half8 u = cvt8(a0, a1);
#pragma unroll
                for (int nt = 0; nt < 4; ++nt) {
                    const half8 bk = *(const half8*)&lds[(nt * 16 + l) * 136 + kk * 32 + quad * 8];
                    akv[rt][nt] = __builtin_amdgcn_mfma_f32_16x16x32_f16(u, bk, akv[rt][nt], 0, 0, 0);
                }
#pragma unroll
                for (int nt = 0; nt < 4; ++nt) {
                    const half8 bv = *(const half8*)&lds[(128 + nt * 16 + l) * 136 + kk * 32 + quad * 8];
                    akv[rt][4 + nt] = __builtin_amdgcn_mfma_f32_16x16x32_f16(u, bv, akv[rt][4 + nt], 0, 0, 0);
                }
                a0 = n0; a1 = n1;
            }
        }
        {   // Q row-tile (own tile's rows)
            const size_t xb = (size_t)(qrow + l) * 64 + kc * 32 + quad * 2;
#pragma unroll
            for (int kk = 0; kk < 4; ++kk) {
                const float4 a0 = xg[xb + kk * 8], a1 = xg[xb + kk * 8 + 1];
                const half8 u = cvt8(a0, a1);
#pragma unroll
                for (int nt = 0; nt < 4; ++nt) {
                    const half8 bq = *(const half8*)&lds[(64 + nt * 16 + l) * 136 + kk * 32 + quad * 8];
                    aq[nt] = __builtin_amdgcn_mfma_f32_16x16x32_f16(u, bq, aq[nt], 0, 0, 0);
                }
            }
        }
        __syncthreads();   // staging readers done (kc=1: frees region for K/V/pool)
    }

    // ---- pack K (scaled) / V to fp16 in regs; q-transpose via own slot ---
    half4v kp[NRT][4], vp[NRT][4];
#pragma unroll
    for (int rt = 0; rt < NRT; ++rt)
#pragma unroll
        for (int nt = 0; nt < 4; ++nt)
#pragma unroll
            for (int r = 0; r < 4; ++r) {
                kp[rt][nt][r] = (_Float16)(akv[rt][nt][r] * 0.125f);
                vp[rt][nt][r] = (_Float16)akv[rt][4 + nt][r];
            }

    _Float16* wh = pool + w * 1088;     // private slot [16][68]
#pragma unroll
    for (int nt = 0; nt < 4; ++nt)
#pragma unroll
        for (int r = 0; r < 4; ++r)
            wh[(quad * 4 + r) * 68 + nt * 16 + l] = (_Float16)aq[nt][r];
    // same-wave readback (compiler orders via lgkmcnt)
    const half8 qf0 = *(const half8*)&wh[l * 68 + quad * 8];
    const half8 qf1 = *(const half8*)&wh[l * 68 + 32 + quad * 8];

    auto write_chunk = [&](int cn) {
        char* Kb = (char*)(Kbuf + (cn & 1) * 4096);
        char* Vb = (char*)(Vbuf + (cn & 1) * 4096);
        const int lr0 = (w - WPC * cn) * RPW;            // 0..64-RPW
#pragma unroll
        for (int rt = 0; rt < NRT; ++rt) {
            const int rb = lr0 + rt * 16;
#pragma unroll
            for (int nt = 0; nt < 4; ++nt) {
#pragma unroll
                for (int r = 0; r < 4; ++r) {
                    const int rr  = rb + quad * 4 + r;
                    const int off = (rr * 128 + (nt * 16 + l) * 2) ^ (((quad * 4 + r) & 7) << 4);
                    *(_Float16*)(Kb + off) = kp[rt][nt][r];
                }
                const int voff = ((nt * 16 + l) * 128 + (rb + quad * 4) * 2) ^ ((l & 7) << 4);
                *(half4v*)(Vb + voff) = vp[rt][nt];
            }
        }
    };

    if (w < WPC) write_chunk(0);        // prologue: chunk 0 into buf 0
    __syncthreads();                    // chunk 0 ready

    // ---- phase 2: s-chunk loop, all softmax state wave-private -----------
    float sums[4] = {0.f, 0.f, 0.f, 0.f};
    floatx4 oacc[4] = {{0.f,0.f,0.f,0.f},{0.f,0.f,0.f,0.f},
                       {0.f,0.f,0.f,0.f},{0.f,0.f,0.f,0.f}};
    const int cmax = t >> 2;            // wave's last chunk (causal)
    const int xorv = (l & 7) << 4;

    for (int c = 0; c < NCH; ++c) {
        // writers stage chunk c+1 into the other buffer (overlaps compute)
        if (c + 1 < NCH && (unsigned)(w - WPC * (c + 1)) < (unsigned)WPC)
            write_chunk(c + 1);

        if (c <= cmax) {
            char* Kb = (char*)(Kbuf + (c & 1) * 4096);
            char* Vb = (char*)(Vbuf + (c & 1) * 4096);
            const int tl = t - 4 * c;
            const int stmaxl = tl < 3 ? tl : 3;

            // pos bands sl=0..4 (bands straddle chunk edges; masked there)
#pragma unroll
            for (int sl = 0; sl <= 4; ++sl) {
                const int st = 4 * c + sl;
                if (st <= t) {
                    const int dt = st - t + 15;
                    const _Float16* rp = rpeh + (size_t)(dt * 16 + l) * 64 + quad * 8;
                    const half8 b0 = *(const half8*)rp;
                    const half8 b1 = *(const half8*)(rp + 32);
                    floatx4 z = {0.f,0.f,0.f,0.f};
                    z = __builtin_amdgcn_mfma_f32_16x16x32_f16(qf0, b0, z, 0, 0, 0);
                    const floatx4 pa = __builtin_amdgcn_mfma_f32_16x16x32_f16(qf1, b1, z, 0, 0, 0);
#pragma unroll
                    for (int r = 0; r < 4; ++r) {
                        const int row = quad * 4 + r;
                        const int col = 16 * sl + l + row - 15;
                        if (sl == 0)      { if (col >= 0) wh[row * 68 + col] = (_Float16)pa[r]; }
                        else if (sl == 4) { if (col < 64) wh[row * 68 + col] = (_Float16)pa[r]; }
                        else                wh[row * 68 + col] = (_Float16)pa[r];
                    }
                }
            }

            // content + exp + private row-sums
#pragma unroll
            for (int sl = 0; sl < 4; ++sl) {
                if (sl <= stmaxl) {
                    const int st = 4 * c + sl;
                    const int rbyte = (sl * 16 + l) * 128;
                    const half8 k0 = *(const half8*)(Kb + ((rbyte + quad * 16) ^ xorv));
                    const half8 k1 = *(const half8*)(Kb + ((rbyte + 64 + quad * 16) ^ xorv));
                    floatx4 z = {0.f,0.f,0.f,0.f};
                    z = __builtin_amdgcn_mfma_f32_16x16x32_f16(qf0, k0, z, 0, 0, 0);
                    const floatx4 sa = __builtin_amdgcn_mfma_f32_16x16x32_f16(qf1, k1, z, 0, 0, 0);
                    const int scol = 16 * sl + l;
                    if (st == t) {      // diagonal: causal predicate
#pragma unroll
                        for (int r = 0; r < 4; ++r) {
                            const int row = quad * 4 + r;
                            float e = 0.f;
                            if (l <= row) e = __expf(sa[r] + (float)wh[row * 68 + scol]);
                            sums[r] += e;
                            wh[row * 68 + scol] = (_Float16)e;
                        }
                    } else {
#pragma unroll
                        for (int r = 0; r < 4; ++r) {
                            const int row = quad * 4 + r;
                            const float e = __expf(sa[r] + (float)wh[row * 68 + scol]);
                            sums[r] += e;
                            wh[row * 68 + scol] = (_Float16)e;
                        }
                    }
                }
            }
            // zero strip covering PV's 32-col read window (diag chunk only)
            if (c == cmax && (stmaxl & 1) == 0) {
                const int zc = 16 * (stmaxl + 1) + l;
#pragma unroll
                for (int r = 0; r < 4; ++r) wh[(quad * 4 + r) * 68 + zc] = (_Float16)0.f;
            }

            // PV accumulate
            const int c2max = stmaxl >> 1;
#pragma unroll
            for (int c2 = 0; c2 < 2; ++c2) {
                if (c2 <= c2max) {
                    const half8 af = *(const half8*)&wh[l * 68 + c2 * 32 + quad * 8];
#pragma unroll
                    for (int ht = 0; ht < 4; ++ht) {
                        const int vo = ((ht * 16 + l) * 128 + c2 * 64 + quad * 16) ^ xorv;
                        const half8 vf = *(const half8*)(Vb + vo);
                        oacc[ht] = __builtin_amdgcn_mfma_f32_16x16x32_f16(af, vf, oacc[ht], 0, 0, 0);
                    }
                }
            }
        }
        __syncthreads();   // chunk c readers done; chunk c+1 buffer ready
    }

    // ---- epilogue: normalize + write out (wave-private) ------------------
    float inv[4];
#pragma unroll
    for (int r = 0; r < 4; ++r) {
        float sv = sums[r];
        sv += __shfl_xor(sv, 1);
        sv += __shfl_xor(sv, 2);
        sv += __shfl_xor(sv, 4);
        sv += __shfl_xor(sv, 8);
        inv[r] = 1.0f / sv;
    }
#pragma unroll
    for (int ht = 0; ht < 4; ++ht)
#pragma unroll
        for (int r = 0; r < 4; ++r)
            out[(size_t)(qrow + quad * 4 + r) * 64 + ht * 16 + l] = oacc[ht][r] * inv[r];
}

__global__ __launch_bounds__(512, 4) void fused(
    const float* __restrict__ x, const _Float16* __restrict__ WT,
    const _Float16* __restrict__ rpeh, float* __restrict__ out)
{
    __shared__ _Float16 lds[26112];     // 51 KB: W-stage | Kbuf+Vbuf+slots
    const int h = blockIdx.x >> 8;      // pairs half0/half1 per CU (round-robin)
    const int b = blockIdx.x & 255;
    if (h == 0) run_half<0>(x, WT, rpeh, out, lds, b, threadIdx.x);
    else        run_half<1>(x, WT, rpeh, out, lds, b, threadIdx.x);
}

extern "C" void kernel_launch(void* const* d_in, const int* in_sizes, int n_in,
                              void* d_out, int out_size, void* d_ws, size_t ws_size,
                              hipStream_t stream) {
    const float* x   = (const float*)d_in[0];
    const float* Wk  = (const float*)d_in[1];
    const float* Wq  = (const float*)d_in[2];
    const float* Wv  = (const float*)d_in[3];
    const float* rpe = (const float*)d_in[4];
    float* out = (float*)d_out;

    _Float16* rpeh = (_Float16*)d_ws;              // [256][64]
    _Float16* WT   = rpeh + 256 * HH;              // [192][256]

    prep<<<dim3(256), dim3(256), 0, stream>>>(rpe, Wk, Wq, Wv, rpeh, WT);
    fused<<<dim3(512), dim3(512), 0, stream>>>(x, WT, rpeh, out);
}

// Round 8
// 147.464 us; speedup vs baseline: 1.2265x; 1.2265x over previous
//
#include <hip/hip_runtime.h>

#define BB 256
#define TT 256
#define HH 64

typedef _Float16 half8 __attribute__((ext_vector_type(8)));
typedef _Float16 half4v __attribute__((ext_vector_type(4)));
typedef __fp16 fp16x2 __attribute__((ext_vector_type(2)));
typedef float floatx4 __attribute__((ext_vector_type(4)));

// ---------------------------------------------------------------------------
// prep: blocks 0..63   -> rpeh[i] = (f16) rpe[i]  (rows 0..255)
//       blocks 64..255 -> WT[(w*64+n)][k] = (f16) W_w[k][n]
// ---------------------------------------------------------------------------
__global__ __launch_bounds__(256) void prep(
    const float* __restrict__ rpe,
    const float* __restrict__ Wk, const float* __restrict__ Wq, const float* __restrict__ Wv,
    _Float16* __restrict__ rpeh, _Float16* __restrict__ WT)
{
    const int bid = blockIdx.x, tid = threadIdx.x;
    if (bid < 64) {
        const int i = bid * 256 + tid;
        rpeh[i] = (_Float16)rpe[i];
    } else {
        const int wsel = (bid - 64) >> 6;          // 0=k, 1=q, 2=v
        const int n    = (bid - 64) & 63;
        const float* W = wsel == 0 ? Wk : (wsel == 1 ? Wq : Wv);
        WT[(size_t)(wsel * 64 + n) * 256 + tid] = (_Float16)W[tid * HH + n];
    }
}

__device__ __forceinline__ half8 cvt8(const float4& a, const float4& b) {
    union H8 { half8 v; fp16x2 p[4]; } u;
    u.p[0] = __builtin_amdgcn_cvt_pkrtz(a.x, a.y);
    u.p[1] = __builtin_amdgcn_cvt_pkrtz(a.z, a.w);
    u.p[2] = __builtin_amdgcn_cvt_pkrtz(b.x, b.y);
    u.p[3] = __builtin_amdgcn_cvt_pkrtz(b.z, b.w);
    return u.v;
}

// ---------------------------------------------------------------------------
// fused r23 = r22 structure, spill-fixed + balanced.
// r22 post-mortem: WRITE_SIZE 62.5MB vs 16.8MB of out = ~46MB scratch spill;
// VGPR_Count=64 but akv alone needs 64 -> __launch_bounds__(512,4) forced a
// 64-VGPR cap and spilled everything else.  93us was the spill, not the
// structure.  Fixes: (1) launch_bounds(512,2) -> 128-VGPR budget, 2 blocks/CU
// co-resident (LDS 51KB x2 = 102KB < 160KB); (2) balanced tile interleave:
// block A tiles {0,2,4,6,9,11,13,15}, B {1,3,5,7,8,10,12,14} (68 units each,
// was 36/100 -> block-level drain); both blocks project all 256 K/V rows
// (32/wave), co-resident pair (b, b+256) shares the same batch's x (L2-hot).
// Retained from r22: shiftless softmax chunked over s (sum+=, O+=, no
// rescale), K/V in projecting wave's regs -> per-chunk double-buffered
// XOR-swizzled K/V tiles [64][64], wave-private slot [16][68] for q/pos/exp
// (stride 68 = conflict-free), barriers only at staging + once per chunk.
// ---------------------------------------------------------------------------
__global__ __launch_bounds__(512, 2) void fused(
    const float* __restrict__ x, const _Float16* __restrict__ WT,
    const _Float16* __restrict__ rpeh, float* __restrict__ out)
{
    __shared__ _Float16 lds[26112];     // 51 KB: W-stage | Kbuf+Vbuf+slots
    _Float16* Kbuf = lds;               // 2 x [64][64] xor-swz (4096 h each)
    _Float16* Vbuf = lds + 8192;        // 2 x [64][64] xor-swz (VT)
    _Float16* pool = lds + 16384;       // 8 waves x [16][68] private slots

    const int tid  = threadIdx.x;
    const int abt  = blockIdx.x >> 8;   // block type: 0=A, 1=B
    const int b    = blockIdx.x & 255;
    const int w    = tid >> 6;
    const int lane = tid & 63;
    const int quad = lane >> 4;
    const int l    = lane & 15;
    const int t    = 2 * w + (((w >> 2) & 1) ^ abt);   // balanced tile map

    const float4* xg = reinterpret_cast<const float4*>(x);
    const int kvrow = b * 256 + 32 * w;       // wave's K/V x-rows (32)
    const int qrow  = b * 256 + 16 * t;       // wave's Q x-rows (own tile)

    floatx4 akv[2][8];                  // [rt][nt]: nt 0..3 = K, 4..7 = V
    floatx4 aq[4];
#pragma unroll
    for (int rt = 0; rt < 2; ++rt)
#pragma unroll
        for (int nt = 0; nt < 8; ++nt) akv[rt][nt] = (floatx4){0.f,0.f,0.f,0.f};
#pragma unroll
    for (int nt = 0; nt < 4; ++nt) aq[nt] = (floatx4){0.f,0.f,0.f,0.f};

    // ---- phase 1: project K,V (own 32 rows) + Q (own tile), 2 k-chunks ---
    for (int kc = 0; kc < 2; ++kc) {
        // stage W chunk kc: [192][136] halves (3072 granules / 512 thr = 6)
#pragma unroll
        for (int i = 0; i < 6; ++i) {
            const int gi = tid + i * 512, row = gi >> 4, g = gi & 15;
            *(half8*)&lds[row * 136 + g * 8] =
                *(const half8*)(WT + (size_t)row * 256 + kc * 128 + g * 8);
        }
        __syncthreads();

#pragma unroll
        for (int rt = 0; rt < 2; ++rt) {
            const size_t xb = (size_t)(kvrow + rt * 16 + l) * 64 + kc * 32 + quad * 2;
#pragma unroll
            for (int kk = 0; kk < 4; ++kk) {
                const float4 a0 = xg[xb + kk * 8], a1 = xg[xb + kk * 8 + 1];
                const half8 u = cvt8(a0, a1);
#pragma unroll
                for (int nt = 0; nt < 4; ++nt) {
                    const half8 bk = *(const half8*)&lds[(nt * 16 + l) * 136 + kk * 32 + quad * 8];
                    akv[rt][nt] = __builtin_amdgcn_mfma_f32_16x16x32_f16(u, bk, akv[rt][nt], 0, 0, 0);
                }
#pragma unroll
                for (int nt = 0; nt < 4; ++nt) {
                    const half8 bv = *(const half8*)&lds[(128 + nt * 16 + l) * 136 + kk * 32 + quad * 8];
                    akv[rt][4 + nt] = __builtin_amdgcn_mfma_f32_16x16x32_f16(u, bv, akv[rt][4 + nt], 0, 0, 0);
                }
            }
        }
        {   // Q row-tile (own tile's rows)
            const size_t xb = (size_t)(qrow + l) * 64 + kc * 32 + quad * 2;
#pragma unroll
            for (int kk = 0; kk < 4; ++kk) {
                const float4 a0 = xg[xb + kk * 8], a1 = xg[xb + kk * 8 + 1];
                const half8 u = cvt8(a0, a1);
#pragma unroll
                for (int nt = 0; nt < 4; ++nt) {
                    const half8 bq = *(const half8*)&lds[(64 + nt * 16 + l) * 136 + kk * 32 + quad * 8];
                    aq[nt] = __builtin_amdgcn_mfma_f32_16x16x32_f16(u, bq, aq[nt], 0, 0, 0);
                }
            }
        }
        __syncthreads();   // staging readers done (kc=1: frees region)
    }

    // ---- pack K (scaled) / V to fp16 in regs; q-transpose via own slot ---
    half4v kp[2][4], vp[2][4];
#pragma unroll
    for (int rt = 0; rt < 2; ++rt)
#pragma unroll
        for (int nt = 0; nt < 4; ++nt)
#pragma unroll
            for (int r = 0; r < 4; ++r) {
                kp[rt][nt][r] = (_Float16)(akv[rt][nt][r] * 0.125f);
                vp[rt][nt][r] = (_Float16)akv[rt][4 + nt][r];
            }

    _Float16* wh = pool + w * 1088;     // private slot [16][68]
#pragma unroll
    for (int nt = 0; nt < 4; ++nt)
#pragma unroll
        for (int r = 0; r < 4; ++r)
            wh[(quad * 4 + r) * 68 + nt * 16 + l] = (_Float16)aq[nt][r];
    // same-wave readback (ordered by lgkmcnt)
    const half8 qf0 = *(const half8*)&wh[l * 68 + quad * 8];
    const half8 qf1 = *(const half8*)&wh[l * 68 + 32 + quad * 8];

    auto write_chunk = [&](int cn) {
        char* Kb = (char*)(Kbuf + (cn & 1) * 4096);
        char* Vb = (char*)(Vbuf + (cn & 1) * 4096);
        const int lr0 = (w - 2 * cn) * 32;               // 0 or 32
#pragma unroll
        for (int rt = 0; rt < 2; ++rt) {
            const int rb = lr0 + rt * 16;
#pragma unroll
            for (int nt = 0; nt < 4; ++nt) {
#pragma unroll
                for (int r = 0; r < 4; ++r) {
                    const int rr  = rb + quad * 4 + r;
                    const int off = (rr * 128 + (nt * 16 + l) * 2) ^ (((quad * 4 + r) & 7) << 4);
                    *(_Float16*)(Kb + off) = kp[rt][nt][r];
                }
                const int voff = ((nt * 16 + l) * 128 + (rb + quad * 4) * 2) ^ ((l & 7) << 4);
                *(half4v*)(Vb + voff) = vp[rt][nt];
            }
        }
    };

    if (w < 2) write_chunk(0);          // prologue: chunk 0 into buf 0
    __syncthreads();                    // chunk 0 ready

    // ---- phase 2: s-chunk loop, softmax state wave-private ---------------
    float sums[4] = {0.f, 0.f, 0.f, 0.f};
    floatx4 oacc[4] = {{0.f,0.f,0.f,0.f},{0.f,0.f,0.f,0.f},
                       {0.f,0.f,0.f,0.f},{0.f,0.f,0.f,0.f}};
    const int cmax = t >> 2;            // wave's last chunk (causal)
    const int xorv = (l & 7) << 4;

    for (int c = 0; c < 4; ++c) {
        // writer waves stage chunk c+1 into the other buffer
        if (c + 1 < 4 && (unsigned)(w - 2 * (c + 1)) < 2u)
            write_chunk(c + 1);

        if (c <= cmax) {
            char* Kb = (char*)(Kbuf + (c & 1) * 4096);
            char* Vb = (char*)(Vbuf + (c & 1) * 4096);
            const int tl = t - 4 * c;
            const int stmaxl = tl < 3 ? tl : 3;

            // pos bands sl=0..4 (straddle chunk edges; masked there)
#pragma unroll
            for (int sl = 0; sl <= 4; ++sl) {
                const int st = 4 * c + sl;
                if (st <= t) {
                    const int dt = st - t + 15;
                    const _Float16* rp = rpeh + (size_t)(dt * 16 + l) * 64 + quad * 8;
                    const half8 b0 = *(const half8*)rp;
                    const half8 b1 = *(const half8*)(rp + 32);
                    floatx4 z = {0.f,0.f,0.f,0.f};
                    z = __builtin_amdgcn_mfma_f32_16x16x32_f16(qf0, b0, z, 0, 0, 0);
                    const floatx4 pa = __builtin_amdgcn_mfma_f32_16x16x32_f16(qf1, b1, z, 0, 0, 0);
#pragma unroll
                    for (int r = 0; r < 4; ++r) {
                        const int row = quad * 4 + r;
                        const int col = 16 * sl + l + row - 15;
                        if (sl == 0)      { if (col >= 0) wh[row * 68 + col] = (_Float16)pa[r]; }
                        else if (sl == 4) { if (col < 64) wh[row * 68 + col] = (_Float16)pa[r]; }
                        else                wh[row * 68 + col] = (_Float16)pa[r];
                    }
                }
            }

            // content + exp + private row-sums
#pragma unroll
            for (int sl = 0; sl < 4; ++sl) {
                if (sl <= stmaxl) {
                    const int st = 4 * c + sl;
                    const int rbyte = (sl * 16 + l) * 128;
                    const half8 k0 = *(const half8*)(Kb + ((rbyte + quad * 16) ^ xorv));
                    const half8 k1 = *(const half8*)(Kb + ((rbyte + 64 + quad * 16) ^ xorv));
                    floatx4 z = {0.f,0.f,0.f,0.f};
                    z = __builtin_amdgcn_mfma_f32_16x16x32_f16(qf0, k0, z, 0, 0, 0);
                    const floatx4 sa = __builtin_amdgcn_mfma_f32_16x16x32_f16(qf1, k1, z, 0, 0, 0);
                    const int scol = 16 * sl + l;
                    if (st == t) {      // diagonal: causal predicate
#pragma unroll
                        for (int r = 0; r < 4; ++r) {
                            const int row = quad * 4 + r;
                            float e = 0.f;
                            if (l <= row) e = __expf(sa[r] + (float)wh[row * 68 + scol]);
                            sums[r] += e;
                            wh[row * 68 + scol] = (_Float16)e;
                        }
                    } else {
#pragma unroll
                        for (int r = 0; r < 4; ++r) {
                            const int row = quad * 4 + r;
                            const float e = __expf(sa[r] + (float)wh[row * 68 + scol]);
                            sums[r] += e;
                            wh[row * 68 + scol] = (_Float16)e;
                        }
                    }
                }
            }
            // zero strip covering PV's 32-col window (diagonal chunk only)
            if (c == cmax && (stmaxl & 1) == 0) {
                const int zc = 16 * (stmaxl + 1) + l;
#pragma unroll
                for (int r = 0; r < 4; ++r) wh[(quad * 4 + r) * 68 + zc] = (_Float16)0.f;
            }

            // PV accumulate
            const int c2max = stmaxl >> 1;
#pragma unroll
            for (int c2 = 0; c2 < 2; ++c2) {
                if (c2 <= c2max) {
                    const half8 af = *(const half8*)&wh[l * 68 + c2 * 32 + quad * 8];
#pragma unroll
                    for (int ht = 0; ht < 4; ++ht) {
                        const int vo = ((ht * 16 + l) * 128 + c2 * 64 + quad * 16) ^ xorv;
                        const half8 vf = *(const half8*)(Vb + vo);
                        oacc[ht] = __builtin_amdgcn_mfma_f32_16x16x32_f16(af, vf, oacc[ht], 0, 0, 0);
                    }
                }
            }
        }
        __syncthreads();   // chunk c readers done; chunk c+1 ready
    }

    // ---- epilogue: normalize + write out (wave-private) ------------------
    float inv[4];
#pragma unroll
    for (int r = 0; r < 4; ++r) {
        float sv = sums[r];
        sv += __shfl_xor(sv, 1);
        sv += __shfl_xor(sv, 2);
        sv += __shfl_xor(sv, 4);
        sv += __shfl_xor(sv, 8);
        inv[r] = 1.0f / sv;
    }
#pragma unroll
    for (int ht = 0; ht < 4; ++ht)
#pragma unroll
        for (int r = 0; r < 4; ++r)
            out[(size_t)(qrow + quad * 4 + r) * 64 + ht * 16 + l] = oacc[ht][r] * inv[r];
}

extern "C" void kernel_launch(void* const* d_in, const int* in_sizes, int n_in,
                              void* d_out, int out_size, void* d_ws, size_t ws_size,
                              hipStream_t stream) {
    const float* x   = (const float*)d_in[0];
    const float* Wk  = (const float*)d_in[1];
    const float* Wq  = (const float*)d_in[2];
    const float* Wv  = (const float*)d_in[3];
    const float* rpe = (const float*)d_in[4];
    float* out = (float*)d_out;

    _Float16* rpeh = (_Float16*)d_ws;              // [256][64]
    _Float16* WT   = rpeh + 256 * HH;              // [192][256]

    prep<<<dim3(256), dim3(256), 0, stream>>>(rpe, Wk, Wq, Wv, rpeh, WT);
    fused<<<dim3(512), dim3(512), 0, stream>>>(x, WT, rpeh, out);
}

// Round 9
// 123.387 us; speedup vs baseline: 1.4658x; 1.1951x over previous
//
#include <hip/hip_runtime.h>

#define BB 256
#define TT 256
#define CC 256
#define HH 64

typedef _Float16 half8 __attribute__((ext_vector_type(8)));
typedef _Float16 half4 __attribute__((ext_vector_type(4)));
typedef __fp16 fp16x2 __attribute__((ext_vector_type(2)));
typedef float floatx4 __attribute__((ext_vector_type(4)));

// ---------------------------------------------------------------------------
// prep: blocks 0..63   -> rpeh[i] = (f16) rpe[i]  (rows 0..255)
//       blocks 64..255 -> WT[(w*64+n)][k] = (f16) W_w[k][n]
// ---------------------------------------------------------------------------
__global__ __launch_bounds__(256) void prep(
    const float* __restrict__ rpe,
    const float* __restrict__ Wk, const float* __restrict__ Wq, const float* __restrict__ Wv,
    _Float16* __restrict__ rpeh, _Float16* __restrict__ WT)
{
    const int bid = blockIdx.x, tid = threadIdx.x;
    if (bid < 64) {
        const int i = bid * 256 + tid;
        rpeh[i] = (_Float16)rpe[i];
    } else {
        const int wsel = (bid - 64) >> 6;          // 0=k, 1=q, 2=v
        const int n    = (bid - 64) & 63;
        const float* W = wsel == 0 ? Wk : (wsel == 1 ? Wq : Wv);
        WT[(size_t)(wsel * 64 + n) * 256 + tid] = (_Float16)W[tid * HH + n];
    }
}

// per-tile exp-weight slot pool: pair j = t>>1 shares width V_j
__device__ __forceinline__ int slot_width(int t) {
    const int j = t >> 1;
    return (j < 2) ? 72 : (32 * j + 40);
}
__device__ __forceinline__ int slot_off(int t) {      // halves, rel. to pool
    const int j = t >> 1;
    const int V = (j < 2) ? 72 : (32 * j + 40);
    const int S = (j == 0) ? 0 : (j == 1) ? 72 : (16 * j * j + 24 * j + 32);
    return 32 * S + (t & 1) * 16 * V;
}

// ---------------------------------------------------------------------------
// fused r24 = r16 skeleton (measured best, 43.4us) with 3 barriers removed.
// r23 post-mortem: spill fixed (WRITE 16.4MB) but 2-block structure doubles
// proj work (FETCH 67MB) and serializes t=15 wave (~98 MFMA alone) -> 78us;
// direction dead.  r16 invariant: LDS ~50% busy, ~50% all-idle stall across
// 9 block-wide barriers.  Removals here:
//  (1) phase 1: stage BOTH W chunks up front (c0->pool, c1->K/VT area,
//      26112h fits the 35328h region written only later); one sync, then
//      c0+c1 compute as a single no-barrier region (was 4 barriers, now 2).
//      c1 x loads issued right after S1 -> latency under c0 compute.
//  (2) B1+B2 merged: epilogue writes K/VT AND q-slots, single visibility
//      sync S3 (pool's last reader already fenced by S2).
//  (3) B4 KEPT -- r20 proved its removal races at the st=8/band-9 seam.
// Barriers: S1,S2,S3,B3,B4,B5 = 6 (was 9).  Phase 2 byte-identical to r16.
// ---------------------------------------------------------------------------
__global__ __launch_bounds__(1024, 4) void fused(
    const float* __restrict__ x, const _Float16* __restrict__ WT,
    const _Float16* __restrict__ rpeh, float* __restrict__ out)
{
    __shared__ _Float16 lds[75264];        // 147 KB: K | VT | pool
    __shared__ float rowsumP[2][256];      // 2-slot row-sum partials
    _Float16* Klds = lds;                  // [256][72]
    _Float16* VT   = lds + 18432;          // [64][264]
    _Float16* pool = lds + 35328;          // 39936 halves (W chunks / slots)

    const int tid  = threadIdx.x;
    const int b    = blockIdx.x;
    const int w    = tid >> 6;
    const int lane = tid & 63;
    const int quad = lane >> 4;
    const int l    = lane & 15;

    union H8 { half8 v; fp16x2 p[4]; };
    const float4* xg = reinterpret_cast<const float4*>(x);
    const int row0g = b * 256 + w * 16;    // wave's 16 x-rows

    floatx4 acc[12];
#pragma unroll
    for (int nt = 0; nt < 12; ++nt) acc[nt] = (floatx4){0.f, 0.f, 0.f, 0.f};

    // ---- phase 1: stage BOTH chunks, then one long compute region --------
    {
        // stage W c0 -> pool, c1 -> lds (K/VT area; written later)
#pragma unroll
        for (int i = 0; i < 3; ++i) {
            const int gi  = tid + i * 1024;
            const int row = gi >> 4;
            const int g   = gi & 15;
            const _Float16* src = WT + (size_t)row * 256 + g * 8;
            *(half8*)&pool[row * 136 + g * 8] = *(const half8*)src;
            *(half8*)&lds[row * 136 + g * 8]  = *(const half8*)(src + 128);
        }
        // x loads chunk 0 (latency under staging + S1)
        float4 xa[4][2];
#pragma unroll
        for (int kk = 0; kk < 4; ++kk) {
            const size_t base = (size_t)(row0g + l) * 64 + kk * 8 + quad * 2;
            xa[kk][0] = xg[base];
            xa[kk][1] = xg[base + 1];
        }
        __syncthreads();                   // S1: both W chunks staged

        // x loads chunk 1 (latency under c0 compute)
        float4 xb[4][2];
#pragma unroll
        for (int kk = 0; kk < 4; ++kk) {
            const size_t base = (size_t)(row0g + l) * 64 + 32 + kk * 8 + quad * 2;
            xb[kk][0] = xg[base];
            xb[kk][1] = xg[base + 1];
        }
        // compute c0 from pool
#pragma unroll
        for (int kk = 0; kk < 4; ++kk) {
            H8 u;
            u.p[0] = __builtin_amdgcn_cvt_pkrtz(xa[kk][0].x, xa[kk][0].y);
            u.p[1] = __builtin_amdgcn_cvt_pkrtz(xa[kk][0].z, xa[kk][0].w);
            u.p[2] = __builtin_amdgcn_cvt_pkrtz(xa[kk][1].x, xa[kk][1].y);
            u.p[3] = __builtin_amdgcn_cvt_pkrtz(xa[kk][1].z, xa[kk][1].w);
#pragma unroll
            for (int nt = 0; nt < 12; ++nt) {
                const half8 bf = *(const half8*)&pool[(nt * 16 + l) * 136 + kk * 32 + quad * 8];
                acc[nt] = __builtin_amdgcn_mfma_f32_16x16x32_f16(u.v, bf, acc[nt], 0, 0, 0);
            }
        }
        // compute c1 from lds (K/VT area)
#pragma unroll
        for (int kk = 0; kk < 4; ++kk) {
            H8 u;
            u.p[0] = __builtin_amdgcn_cvt_pkrtz(xb[kk][0].x, xb[kk][0].y);
            u.p[1] = __builtin_amdgcn_cvt_pkrtz(xb[kk][0].z, xb[kk][0].w);
            u.p[2] = __builtin_amdgcn_cvt_pkrtz(xb[kk][1].x, xb[kk][1].y);
            u.p[3] = __builtin_amdgcn_cvt_pkrtz(xb[kk][1].z, xb[kk][1].w);
#pragma unroll
            for (int nt = 0; nt < 12; ++nt) {
                const half8 bf = *(const half8*)&lds[(nt * 16 + l) * 136 + kk * 32 + quad * 8];
                acc[nt] = __builtin_amdgcn_mfma_f32_16x16x32_f16(u.v, bf, acc[nt], 0, 0, 0);
            }
        }
        __syncthreads();                   // S2: W readers done everywhere
    }

    // ---- epilogue: K (scaled), VT, q-slots -- one visibility barrier -----
    _Float16* wh = pool + slot_off(w);
    const int Vw = slot_width(w);
    {
        const int trw = w * 16;
#pragma unroll
        for (int nt = 0; nt < 4; ++nt) {
#pragma unroll
            for (int r = 0; r < 4; ++r) {
                Klds[(trw + quad * 4 + r) * 72 + nt * 16 + l] = (_Float16)(acc[nt][r] * 0.125f);
                wh[(quad * 4 + r) * Vw + nt * 16 + l] = (_Float16)acc[nt + 4][r];
            }
            half4 vv;
            vv[0] = (_Float16)acc[nt + 8][0];
            vv[1] = (_Float16)acc[nt + 8][1];
            vv[2] = (_Float16)acc[nt + 8][2];
            vv[3] = (_Float16)acc[nt + 8][3];
            *(half4*)&VT[(nt * 16 + l) * 264 + trw + quad * 4] = vv;
        }
    }
    if (tid < 512) ((float*)rowsumP)[tid] = 0.f;
    __syncthreads();       // S3: K/VT/q visible block-wide

    // read q A-frags: own + partner (partner slot q-region not yet clobbered)
    const half8 qf0 = *(const half8*)&wh[l * Vw + quad * 8];
    const half8 qf1 = *(const half8*)&wh[l * Vw + 32 + quad * 8];
    const int tp = 15 - w;
    _Float16* whp = pool + slot_off(tp);
    const int Vp = slot_width(tp);
    half8 qg0 = qf0, qg1 = qf1;
    if (w < 8) {
        qg0 = *(const half8*)&whp[l * Vp + quad * 8];
        qg1 = *(const half8*)&whp[l * Vp + 32 + quad * 8];
    }
    __syncthreads();       // B3: q consumed everywhere; slots writable

    // ---- phase 2b: pos scores (skewed scatter), balanced -----------------
    const int jmaxo = (w < 8) ? w : 8;     // own bands j=0..jmaxo
#pragma unroll
    for (int j = 0; j < 9; ++j) {
        if (j <= jmaxo) {
            const int dt = j + 15 - w;
            const _Float16* rp = rpeh + (size_t)(dt * 16 + l) * HH + quad * 8;
            const half8 bf0 = *(const half8*)rp;
            const half8 bf1 = *(const half8*)(rp + 32);
            floatx4 z = {0.f, 0.f, 0.f, 0.f};
            z = __builtin_amdgcn_mfma_f32_16x16x32_f16(qf0, bf0, z, 0, 0, 0);
            const floatx4 pacc = __builtin_amdgcn_mfma_f32_16x16x32_f16(qf1, bf1, z, 0, 0, 0);
            if (j == 0) {
#pragma unroll
                for (int r = 0; r < 4; ++r) {
                    const int row = quad * 4 + r;
                    const int s   = l + row - 15;
                    if (s >= 0) wh[row * Vw + s] = (_Float16)pacc[r];
                }
            } else {
#pragma unroll
                for (int r = 0; r < 4; ++r) {
                    const int row = quad * 4 + r;
                    wh[row * Vw + 16 * j + l + row - 15] = (_Float16)pacc[r];
                }
            }
        }
    }
    if (w < 8) {                            // partner bands j=9..15-w (s>=129)
#pragma unroll
        for (int j = 9; j < 16; ++j) {
            if (j <= 15 - w) {
                const int dt = j + w;
                const _Float16* rp = rpeh + (size_t)(dt * 16 + l) * HH + quad * 8;
                const half8 bf0 = *(const half8*)rp;
                const half8 bf1 = *(const half8*)(rp + 32);
                floatx4 z = {0.f, 0.f, 0.f, 0.f};
                z = __builtin_amdgcn_mfma_f32_16x16x32_f16(qg0, bf0, z, 0, 0, 0);
                const floatx4 pacc = __builtin_amdgcn_mfma_f32_16x16x32_f16(qg1, bf1, z, 0, 0, 0);
#pragma unroll
                for (int r = 0; r < 4; ++r) {
                    const int row = quad * 4 + r;
                    whp[row * Vp + 16 * j + l + row - 15] = (_Float16)pacc[r];
                }
            }
        }
    }
    __syncthreads();       // B4: tiles t>=9 read partner band 9 at st=8

    // ---- phase 2c: content scores + exp + partial row-sums ---------------
    {
        float sumsA[4] = {0.f, 0.f, 0.f, 0.f};
#pragma unroll
        for (int st = 0; st < 9; ++st) {
            if (st <= jmaxo) {
                const _Float16* kp = &Klds[(st * 16 + l) * 72 + quad * 8];
                const half8 kf0 = *(const half8*)kp;
                const half8 kf1 = *(const half8*)(kp + 32);
                floatx4 z = {0.f, 0.f, 0.f, 0.f};
                z = __builtin_amdgcn_mfma_f32_16x16x32_f16(qf0, kf0, z, 0, 0, 0);
                const floatx4 sacc = __builtin_amdgcn_mfma_f32_16x16x32_f16(qf1, kf1, z, 0, 0, 0);
                const int s = l + 16 * st;
                if (st == w) {             // own diagonal (only w<=8)
#pragma unroll
                    for (int r = 0; r < 4; ++r) {
                        const int row = quad * 4 + r;
                        float e = 0.f;
                        if (l <= row) e = __expf(sacc[r] + (float)wh[row * Vw + s]);
                        sumsA[r] += e;
                        wh[row * Vw + s] = (_Float16)e;
                    }
                    if ((w & 1) == 0) {    // zero strip covering PV read window
                        const int s2 = l + 16 * (st + 1);
#pragma unroll
                        for (int r = 0; r < 4; ++r) wh[(quad * 4 + r) * Vw + s2] = (_Float16)0.f;
                    }
                } else {
#pragma unroll
                    for (int r = 0; r < 4; ++r) {
                        const int row = quad * 4 + r;
                        const float e = __expf(sacc[r] + (float)wh[row * Vw + s]);
                        sumsA[r] += e;
                        wh[row * Vw + s] = (_Float16)e;
                    }
                }
            }
        }
#pragma unroll
        for (int r = 0; r < 4; ++r) {
            float sv = sumsA[r];
            sv += __shfl_xor(sv, 1);
            sv += __shfl_xor(sv, 2);
            sv += __shfl_xor(sv, 4);
            sv += __shfl_xor(sv, 8);
            if (l == 0) rowsumP[0][16 * w + quad * 4 + r] = sv;
        }
    }
    if (w < 8) {                            // partner tiles st=9..15-w
        float sumsB[4] = {0.f, 0.f, 0.f, 0.f};
#pragma unroll
        for (int st = 9; st < 16; ++st) {
            if (st <= 15 - w) {
                const _Float16* kp = &Klds[(st * 16 + l) * 72 + quad * 8];
                const half8 kf0 = *(const half8*)kp;
                const half8 kf1 = *(const half8*)(kp + 32);
                floatx4 z = {0.f, 0.f, 0.f, 0.f};
                z = __builtin_amdgcn_mfma_f32_16x16x32_f16(qg0, kf0, z, 0, 0, 0);
                const floatx4 sacc = __builtin_amdgcn_mfma_f32_16x16x32_f16(qg1, kf1, z, 0, 0, 0);
                const int s = l + 16 * st;
                if (st == tp) {            // partner diagonal
#pragma unroll
                    for (int r = 0; r < 4; ++r) {
                        const int row = quad * 4 + r;
                        float e = 0.f;
                        if (l <= row) e = __expf(sacc[r] + (float)whp[row * Vp + s]);
                        sumsB[r] += e;
                        whp[row * Vp + s] = (_Float16)e;
                    }
                    if ((tp & 1) == 0) {
                        const int s2 = l + 16 * (st + 1);
#pragma unroll
                        for (int r = 0; r < 4; ++r) whp[(quad * 4 + r) * Vp + s2] = (_Float16)0.f;
                    }
                } else {
#pragma unroll
                    for (int r = 0; r < 4; ++r) {
                        const int row = quad * 4 + r;
                        const float e = __expf(sacc[r] + (float)whp[row * Vp + s]);
                        sumsB[r] += e;
                        whp[row * Vp + s] = (_Float16)e;
                    }
                }
            }
        }
#pragma unroll
        for (int r = 0; r < 4; ++r) {
            float sv = sumsB[r];
            sv += __shfl_xor(sv, 1);
            sv += __shfl_xor(sv, 2);
            sv += __shfl_xor(sv, 4);
            sv += __shfl_xor(sv, 8);
            if (l == 0) rowsumP[1][16 * tp + quad * 4 + r] = sv;
        }
    }
    __syncthreads();       // B5: exp-weights + row-sums complete

    // ---- phase 2d: PV, paired (t1, 15-t1) x 2 head-tiles -> 18 MFMA/wave -
    {
        const int t1 = w >> 1;
        const int hb = (w & 1) << 1;
#pragma unroll
        for (int sel = 0; sel < 2; ++sel) {
            const int tt = sel ? (15 - t1) : t1;
            const _Float16* ws = pool + slot_off(tt);
            const int Vt    = slot_width(tt);
            const int cmaxt = tt >> 1;
            float inv[4];
#pragma unroll
            for (int r = 0; r < 4; ++r) {
                const int row = 16 * tt + quad * 4 + r;
                inv[r] = 1.0f / (rowsumP[0][row] + rowsumP[1][row]);
            }
            floatx4 o0 = {0.f, 0.f, 0.f, 0.f};
            floatx4 o1 = {0.f, 0.f, 0.f, 0.f};
#pragma unroll
            for (int c = 0; c < 8; ++c) {
                if (c <= cmaxt) {
                    const half8 af  = *(const half8*)&ws[l * Vt + c * 32 + quad * 8];
                    const half8 vf0 = *(const half8*)&VT[((hb + 0) * 16 + l) * 264 + c * 32 + quad * 8];
                    const half8 vf1 = *(const half8*)&VT[((hb + 1) * 16 + l) * 264 + c * 32 + quad * 8];
                    o0 = __builtin_amdgcn_mfma_f32_16x16x32_f16(af, vf0, o0, 0, 0, 0);
                    o1 = __builtin_amdgcn_mfma_f32_16x16x32_f16(af, vf1, o1, 0, 0, 0);
                }
            }
#pragma unroll
            for (int r = 0; r < 4; ++r) {
                const int t = 16 * tt + quad * 4 + r;
                out[(size_t)(b * TT + t) * HH + (hb + 0) * 16 + l] = o0[r] * inv[r];
                out[(size_t)(b * TT + t) * HH + (hb + 1) * 16 + l] = o1[r] * inv[r];
            }
        }
    }
}

extern "C" void kernel_launch(void* const* d_in, const int* in_sizes, int n_in,
                              void* d_out, int out_size, void* d_ws, size_t ws_size,
                              hipStream_t stream) {
    const float* x   = (const float*)d_in[0];
    const float* Wk  = (const float*)d_in[1];
    const float* Wq  = (const float*)d_in[2];
    const float* Wv  = (const float*)d_in[3];
    const float* rpe = (const float*)d_in[4];
    float* out = (float*)d_out;

    _Float16* rpeh = (_Float16*)d_ws;              // [256][64]
    _Float16* WT   = rpeh + 256 * HH;              // [192][256]

    prep<<<dim3(256), dim3(256), 0, stream>>>(rpe, Wk, Wq, Wv, rpeh, WT);
    fused<<<dim3(BB), dim3(1024), 0, stream>>>(x, WT, rpeh, out);
}